// Round 8
// baseline (258.743 us; speedup 1.0000x reference)
//
#include <hip/hip_runtime.h>
#include <hip/hip_bf16.h>

typedef unsigned short u16;
typedef __attribute__((ext_vector_type(8))) short short8;
typedef __attribute__((ext_vector_type(4))) float floatx4;

#define BATCH 16
#define CDIM 512
#define NSPAT 1024
#define NGROUP 8

__device__ __forceinline__ u16 f2bf(float f) {
    unsigned u = __float_as_uint(f);
    u += 0x7FFFu + ((u >> 16) & 1u);   // RNE
    return (u16)(u >> 16);
}

__device__ __forceinline__ void load_lds16(const void* g, void* l) {
    __builtin_amdgcn_global_load_lds(
        (const __attribute__((address_space(1))) unsigned int*)g,
        (__attribute__((address_space(3))) unsigned int*)l, 16, 0, 0);
}

// ---------------- prep: weights->bf16 + GroupNorm stats + lsums zero (one launch) ----------------
// blocks [0,768): w_qkv cvt; [768,1024): w_proj cvt; [1024,1152): gn stats; [1152,1168): zero lsums
__global__ __launch_bounds__(256) void prep_kernel(
    const float* __restrict__ w_qkv, const float* __restrict__ w_proj,
    u16* __restrict__ wqkv_bf, u16* __restrict__ wproj_bf,
    const float* __restrict__ x, float* __restrict__ stats, float* __restrict__ lsums) {
    int b = blockIdx.x;
    if (b < 1024) {
        const float* src = (b < 768) ? w_qkv : w_proj;
        u16* dst = (b < 768) ? wqkv_bf : wproj_bf;
        int i = (b < 768 ? b : b - 768) * 256 + threadIdx.x;
        float4 v = ((const float4*)src)[i];
        ushort4 o;
        o.x = f2bf(v.x); o.y = f2bf(v.y); o.z = f2bf(v.z); o.w = f2bf(v.w);
        ((ushort4*)dst)[i] = o;
        return;
    }
    if (b >= 1152) {  // zero lsums: 16 blocks x 256 threads x float4 = 16384 floats
        ((float4*)lsums)[(b - 1152) * 256 + threadIdx.x] = (float4){0.f, 0.f, 0.f, 0.f};
        return;
    }
    __shared__ float rs[4], rss[4];
    int bg = b - 1024;  // 0..127; one group = 65536 contiguous floats
    const float4* xv = (const float4*)(x + (size_t)bg * 65536);
    float s = 0.f, ss = 0.f;
    for (int i = threadIdx.x; i < 16384; i += 256) {
        float4 v = xv[i];
        s += v.x + v.y + v.z + v.w;
        ss += v.x * v.x + v.y * v.y + v.z * v.z + v.w * v.w;
    }
#pragma unroll
    for (int off = 32; off; off >>= 1) { s += __shfl_down(s, off); ss += __shfl_down(ss, off); }
    int wave = threadIdx.x >> 6, lane = threadIdx.x & 63;
    if (lane == 0) { rs[wave] = s; rss[wave] = ss; }
    __syncthreads();
    if (threadIdx.x == 0) {
        float S1 = rs[0] + rs[1] + rs[2] + rs[3];
        float S2 = rss[0] + rss[1] + rss[2] + rss[3];
        float mean = S1 * (1.f / 65536.f);
        float var = S2 * (1.f / 65536.f) - mean * mean;
        stats[bg * 2] = mean;
        stats[bg * 2 + 1] = rsqrtf(var + 1e-5f);
    }
}

// ---------------- GroupNorm apply + transpose: x[b][c][n] fp32 -> hT[b][n][c] bf16 ----------------
#define TSTR 66
__global__ __launch_bounds__(256) void gn_transpose_kernel(
    const float* __restrict__ x, const float* __restrict__ gamma, const float* __restrict__ beta,
    const float* __restrict__ stats, u16* __restrict__ hT) {
    __shared__ u16 t[64 * TSTR];
    int b = blockIdx.z, c0 = blockIdx.y << 6, n0 = blockIdx.x << 6;
    int tid = threadIdx.x;
    const float* xb = x + ((size_t)b * CDIM + c0) * NSPAT + n0;
#pragma unroll
    for (int p = 0; p < 4; ++p) {
        int cl = p * 16 + (tid >> 4);
        int nl = (tid & 15) << 2;
        int c = c0 + cl;
        int bg = b * NGROUP + (c >> 6);
        float ga = gamma[c] * stats[bg * 2 + 1];
        float be = beta[c] - stats[bg * 2] * ga;
        float4 v = *(const float4*)(xb + (size_t)cl * NSPAT + nl);
        u16* dst = &t[cl * TSTR + nl];
        dst[0] = f2bf(v.x * ga + be);
        dst[1] = f2bf(v.y * ga + be);
        dst[2] = f2bf(v.z * ga + be);
        dst[3] = f2bf(v.w * ga + be);
    }
    __syncthreads();
    u16* hb = hT + ((size_t)b * NSPAT + n0) * CDIM + c0;
#pragma unroll
    for (int p = 0; p < 4; ++p) {
        int nl = p * 16 + (tid >> 4);
        int cl4 = (tid & 15) << 2;
        ushort4 o;
        o.x = t[(cl4 + 0) * TSTR + nl];
        o.y = t[(cl4 + 1) * TSTR + nl];
        o.z = t[(cl4 + 2) * TSTR + nl];
        o.w = t[(cl4 + 3) * TSTR + nl];
        *(ushort4*)(hb + (size_t)nl * CDIM + cl4) = o;
    }
}

// ---------------- BMv x 128 x 64 bf16 MFMA GEMM, global_load_lds + XOR-swizzled LDS ----------------
// LDS tile rows x 64 shorts (8 chunks of 16B). Slot (r,p) holds global k-chunk p^(r&7);
// reader of (R, chunk q) uses p = q^(R&7) -> conflict-free (2-way max, free).
// A: bf16 [M][lda] k-contig rows, B: bf16 [N][ldb] k-contig rows. Waves 2x2; wave out = (BMv/2)x64.
// EPI 0: qkv  — +bias[R]; blockIdx.y<8 -> transposed bf16 out0[col][R] (ldc), else natural out1
// EPI 1: scores -> P = exp(acc*scale) bf16 natural; fused row sums atomicAdd into lsums
// EPI 2: PV   — *rcp(lsums[col]), transposed bf16 out0[col][R] (ldc)
// EPI 3: proj — +bias[R]+resid, fp32 natural out0 (ldc)
template <int EPI, int BMv>
__global__ __launch_bounds__(256) void gemm128(
    const u16* __restrict__ A, const u16* __restrict__ B, int K, int lda, int ldb,
    unsigned long sA, unsigned long sB,
    void* __restrict__ out0, unsigned long s0, int ldc,
    void* __restrict__ out1, unsigned long s1,
    const float* __restrict__ bias, float* __restrict__ lsums,
    const float* __restrict__ resid, unsigned long sR, float scale) {
    constexpr int MI = BMv / 32;           // i-tiles per wave
    __shared__ u16 As[BMv * 64];
    __shared__ u16 Bs[128 * 64];
    int tid = threadIdx.x;
    int lane = tid & 63;
    int wave = tid >> 6;
    int quad = lane >> 4;
    int lrow = lane & 15;
    int wm = (wave >> 1) * (BMv / 2);
    int wn = (wave & 1) << 6;
    int m0 = blockIdx.y * BMv;
    int n0 = blockIdx.x << 7;
    const u16* Ab = A + sA * blockIdx.z;
    const u16* Bb = B + sB * blockIdx.z;

    floatx4 acc[MI][4];
#pragma unroll
    for (int i = 0; i < MI; ++i)
#pragma unroll
        for (int j = 0; j < 4; ++j) acc[i][j] = (floatx4){0.f, 0.f, 0.f, 0.f};

    for (int k0 = 0; k0 < K; k0 += 64) {
#pragma unroll
        for (int it = 0; it < (BMv * 8) / 256; ++it) {
            int c = it * 256 + tid;             // A: BMv*8 chunks of 16B
            int r = c >> 3, p = c & 7;
            int kc = p ^ (r & 7);
            load_lds16(Ab + (size_t)(m0 + r) * lda + k0 + (kc << 3), &As[c << 3]);
        }
#pragma unroll
        for (int it = 0; it < 4; ++it) {
            int c = it * 256 + tid;             // B: 1024 chunks
            int r = c >> 3, p = c & 7;
            int kc = p ^ (r & 7);
            load_lds16(Bb + (size_t)(n0 + r) * ldb + k0 + (kc << 3), &Bs[c << 3]);
        }
        __syncthreads();
#pragma unroll
        for (int s = 0; s < 2; ++s) {
            short8 af[MI], bf[4];
#pragma unroll
            for (int i = 0; i < MI; ++i) {
                int R = wm + i * 16 + lrow;
                int p = (s * 4 + quad) ^ (R & 7);
                af[i] = *(const short8*)&As[(R << 6) + (p << 3)];
            }
#pragma unroll
            for (int j = 0; j < 4; ++j) {
                int R = wn + j * 16 + lrow;
                int p = (s * 4 + quad) ^ (R & 7);
                bf[j] = *(const short8*)&Bs[(R << 6) + (p << 3)];
            }
#pragma unroll
            for (int i = 0; i < MI; ++i)
#pragma unroll
                for (int j = 0; j < 4; ++j)
                    acc[i][j] = __builtin_amdgcn_mfma_f32_16x16x32_bf16(af[i], bf[j], acc[i][j], 0, 0, 0);
        }
        __syncthreads();
    }

    if (EPI == 0) {
        if (blockIdx.y < 8) {  // q,k rows (<1024): transposed store
            u16* qk = (u16*)out0 + s0 * blockIdx.z;
#pragma unroll
            for (int i = 0; i < MI; ++i)
#pragma unroll
                for (int j = 0; j < 4; ++j) {
                    int R0 = m0 + wm + i * 16 + (quad << 2);
                    int Cc = n0 + wn + j * 16 + lrow;
                    ushort4 pk;
                    pk.x = f2bf(acc[i][j][0] + bias[R0 + 0]);
                    pk.y = f2bf(acc[i][j][1] + bias[R0 + 1]);
                    pk.z = f2bf(acc[i][j][2] + bias[R0 + 2]);
                    pk.w = f2bf(acc[i][j][3] + bias[R0 + 3]);
                    *(ushort4*)&qk[(size_t)Cc * ldc + R0] = pk;
                }
        } else {  // v rows: natural store
            u16* vb = (u16*)out1 + s1 * blockIdx.z;
#pragma unroll
            for (int i = 0; i < MI; ++i)
#pragma unroll
                for (int j = 0; j < 4; ++j)
#pragma unroll
                    for (int r = 0; r < 4; ++r) {
                        int R = m0 + wm + i * 16 + (quad << 2) + r;
                        int Cc = n0 + wn + j * 16 + lrow;
                        vb[(size_t)(R - 1024) * NSPAT + Cc] = f2bf(acc[i][j][r] + bias[R]);
                    }
        }
    } else if (EPI == 1) {
        u16* Pp = (u16*)out0 + s0 * blockIdx.z;
        float rowpart[MI][4];
#pragma unroll
        for (int i = 0; i < MI; ++i)
#pragma unroll
            for (int r = 0; r < 4; ++r) rowpart[i][r] = 0.f;
#pragma unroll
        for (int i = 0; i < MI; ++i)
#pragma unroll
            for (int j = 0; j < 4; ++j)
#pragma unroll
                for (int r = 0; r < 4; ++r) {
                    int R = m0 + wm + i * 16 + (quad << 2) + r;
                    int Cc = n0 + wn + j * 16 + lrow;
                    float e = __expf(acc[i][j][r] * scale);
                    rowpart[i][r] += e;
                    Pp[(size_t)R * ldc + Cc] = f2bf(e);
                }
        // reduce across the 16 lanes of each quad (they share rows, differ in cols)
#pragma unroll
        for (int i = 0; i < MI; ++i)
#pragma unroll
            for (int r = 0; r < 4; ++r) {
                float v = rowpart[i][r];
#pragma unroll
                for (int m = 1; m < 16; m <<= 1) v += __shfl_xor(v, m);
                if (lrow == 0) {
                    int R = m0 + wm + i * 16 + (quad << 2) + r;
                    atomicAdd(&lsums[(size_t)blockIdx.z * NSPAT + R], v);
                }
            }
    } else if (EPI == 2) {
        u16* OT = (u16*)out0 + s0 * blockIdx.z;
        const float* li = lsums + (size_t)blockIdx.z * NSPAT;
#pragma unroll
        for (int i = 0; i < MI; ++i)
#pragma unroll
            for (int j = 0; j < 4; ++j) {
                int R0 = m0 + wm + i * 16 + (quad << 2);
                int Cc = n0 + wn + j * 16 + lrow;
                float sc = __builtin_amdgcn_rcpf(li[Cc]);
                ushort4 pk;
                pk.x = f2bf(acc[i][j][0] * sc);
                pk.y = f2bf(acc[i][j][1] * sc);
                pk.z = f2bf(acc[i][j][2] * sc);
                pk.w = f2bf(acc[i][j][3] * sc);
                *(ushort4*)&OT[(size_t)Cc * ldc + R0] = pk;
            }
    } else {
        float* Op = (float*)out0 + s0 * blockIdx.z;
        const float* xr = resid + sR * blockIdx.z;
#pragma unroll
        for (int i = 0; i < MI; ++i)
#pragma unroll
            for (int j = 0; j < 4; ++j)
#pragma unroll
                for (int r = 0; r < 4; ++r) {
                    int R = m0 + wm + i * 16 + (quad << 2) + r;
                    int Cc = n0 + wn + j * 16 + lrow;
                    size_t off = (size_t)R * ldc + Cc;
                    Op[off] = acc[i][j][r] + bias[R] + xr[off];
                }
    }
}

// ---------------- launch ----------------
extern "C" void kernel_launch(void* const* d_in, const int* in_sizes, int n_in,
                              void* d_out, int out_size, void* d_ws, size_t ws_size,
                              hipStream_t stream) {
    const float* x      = (const float*)d_in[0];
    const float* gamma  = (const float*)d_in[1];
    const float* beta   = (const float*)d_in[2];
    const float* w_qkv  = (const float*)d_in[3];
    const float* b_qkv  = (const float*)d_in[4];
    const float* w_proj = (const float*)d_in[5];
    const float* b_proj = (const float*)d_in[6];
    float* out = (float*)d_out;

    const size_t CN = (size_t)CDIM * NSPAT;   // 524288
    const size_t NN = (size_t)NSPAT * NSPAT;  // 1048576
    const float SCALE = 0.044194173824159216f;

    // Workspace layout (~120 MB; ws >= 186.5 MB proven in round 4):
    char* ws = (char*)d_ws;
    float* stats  = (float*)ws;                                   // 4 KB
    u16* wqkv_bf  = (u16*)(ws + 4096);                            // 1.5 MB
    u16* wproj_bf = wqkv_bf + (size_t)3 * CDIM * CDIM;            // 0.5 MB
    u16* hT       = wproj_bf + (size_t)CDIM * CDIM;               // 16.8 MB  [n][c] bf16
    u16* qkT      = hT + BATCH * CN;                              // 33.5 MB  [n][o<1024] bf16
    u16* v_bf     = qkT + BATCH * NN;                             // 16.8 MB  [c][n] bf16
    u16* OT       = v_bf + BATCH * CN;                            // 16.8 MB  [i][c] bf16
    u16* P        = OT + BATCH * CN;                              // 33.5 MB  [i][j] bf16 (unnormalized)
    float* lsums  = (float*)(P + BATCH * NN);                     // 64 KB raw softmax denominators

    prep_kernel<<<1168, 256, 0, stream>>>(w_qkv, w_proj, wqkv_bf, wproj_bf, x, stats, lsums);

    gn_transpose_kernel<<<dim3(NSPAT / 64, CDIM / 64, BATCH), 256, 0, stream>>>(
        x, gamma, beta, stats, hT);

    // qkv: M=1536 (o), N=1024 (n), K=512 (c). A=W_qkv bf16 [o][c], B=hT [n][c].
    gemm128<0, 128><<<dim3(8, 12, BATCH), 256, 0, stream>>>(
        wqkv_bf, hT, CDIM, CDIM, CDIM, 0ul, CN,
        qkT, NN, NSPAT, v_bf, CN, b_qkv, nullptr, nullptr, 0ul, 0.f);

    // scores->P: M=i, N=j, K=c=512. A=qT, B=kT. P = exp(scale*acc); fused row sums.
    gemm128<1, 128><<<dim3(8, 8, BATCH), 256, 0, stream>>>(
        qkT, qkT + CDIM, CDIM, NSPAT, NSPAT, NN, NN,
        P, NN, NSPAT, nullptr, 0ul, nullptr, lsums, nullptr, 0ul, SCALE);

    // PV: M=c (512), N=i (1024), K=j (1024). A=v[c][j], B=P[i][j]. BM=64 -> 1024 blocks.
    // Epilogue: *rcp(lsums[i]), out OT[i][c] (ldc=512).
    gemm128<2, 64><<<dim3(8, 8, BATCH), 256, 0, stream>>>(
        v_bf, P, NSPAT, NSPAT, NSPAT, CN, NN,
        OT, CN, CDIM, nullptr, 0ul, nullptr, lsums, nullptr, 0ul, 0.f);

    // proj: M=o (512), N=n (1024), K=c=512. A=W_proj bf16, B=OT[n][c]. BM=64 -> 1024 blocks.
    gemm128<3, 64><<<dim3(8, 8, BATCH), 256, 0, stream>>>(
        wproj_bf, OT, CDIM, CDIM, CDIM, 0ul, CN,
        out, CN, NSPAT, nullptr, 0ul, b_proj, nullptr, x, CN, 0.f);
}

// Round 9
// 252.000 us; speedup vs baseline: 1.0268x; 1.0268x over previous
//
#include <hip/hip_runtime.h>
#include <hip/hip_bf16.h>

typedef unsigned short u16;
typedef __attribute__((ext_vector_type(8))) short short8;
typedef __attribute__((ext_vector_type(4))) float floatx4;

#define BATCH 16
#define CDIM 512
#define NSPAT 1024
#define NGROUP 8
#define QKV3 1536

__device__ __forceinline__ u16 f2bf(float f) {
    unsigned u = __float_as_uint(f);
    u += 0x7FFFu + ((u >> 16) & 1u);   // RNE
    return (u16)(u >> 16);
}

__device__ __forceinline__ void load_lds16(const void* g, void* l) {
    __builtin_amdgcn_global_load_lds(
        (const __attribute__((address_space(1))) unsigned int*)g,
        (__attribute__((address_space(3))) unsigned int*)l, 16, 0, 0);
}

// ---------------- prep: weights->bf16 + GroupNorm stats + lsums zero ----------------
__global__ __launch_bounds__(256) void prep_kernel(
    const float* __restrict__ w_qkv, const float* __restrict__ w_proj,
    u16* __restrict__ wqkv_bf, u16* __restrict__ wproj_bf,
    const float* __restrict__ x, float* __restrict__ stats, float* __restrict__ lsums) {
    int b = blockIdx.x;
    if (b < 1024) {
        const float* src = (b < 768) ? w_qkv : w_proj;
        u16* dst = (b < 768) ? wqkv_bf : wproj_bf;
        int i = (b < 768 ? b : b - 768) * 256 + threadIdx.x;
        float4 v = ((const float4*)src)[i];
        ushort4 o;
        o.x = f2bf(v.x); o.y = f2bf(v.y); o.z = f2bf(v.z); o.w = f2bf(v.w);
        ((ushort4*)dst)[i] = o;
        return;
    }
    if (b >= 1152) {  // zero lsums
        ((float4*)lsums)[(b - 1152) * 256 + threadIdx.x] = (float4){0.f, 0.f, 0.f, 0.f};
        return;
    }
    __shared__ float rs[4], rss[4];
    int bg = b - 1024;
    const float4* xv = (const float4*)(x + (size_t)bg * 65536);
    float s = 0.f, ss = 0.f;
    for (int i = threadIdx.x; i < 16384; i += 256) {
        float4 v = xv[i];
        s += v.x + v.y + v.z + v.w;
        ss += v.x * v.x + v.y * v.y + v.z * v.z + v.w * v.w;
    }
#pragma unroll
    for (int off = 32; off; off >>= 1) { s += __shfl_down(s, off); ss += __shfl_down(ss, off); }
    int wave = threadIdx.x >> 6, lane = threadIdx.x & 63;
    if (lane == 0) { rs[wave] = s; rss[wave] = ss; }
    __syncthreads();
    if (threadIdx.x == 0) {
        float S1 = rs[0] + rs[1] + rs[2] + rs[3];
        float S2 = rss[0] + rss[1] + rss[2] + rss[3];
        float mean = S1 * (1.f / 65536.f);
        float var = S2 * (1.f / 65536.f) - mean * mean;
        stats[bg * 2] = mean;
        stats[bg * 2 + 1] = rsqrtf(var + 1e-5f);
    }
}

// ---------------- GroupNorm apply + transpose: x[b][c][n] fp32 -> hT[b][n][c] bf16 ----------------
#define TSTR 66
__global__ __launch_bounds__(256) void gn_transpose_kernel(
    const float* __restrict__ x, const float* __restrict__ gamma, const float* __restrict__ beta,
    const float* __restrict__ stats, u16* __restrict__ hT) {
    __shared__ u16 t[64 * TSTR];
    int b = blockIdx.z, c0 = blockIdx.y << 6, n0 = blockIdx.x << 6;
    int tid = threadIdx.x;
    const float* xb = x + ((size_t)b * CDIM + c0) * NSPAT + n0;
#pragma unroll
    for (int p = 0; p < 4; ++p) {
        int cl = p * 16 + (tid >> 4);
        int nl = (tid & 15) << 2;
        int c = c0 + cl;
        int bg = b * NGROUP + (c >> 6);
        float ga = gamma[c] * stats[bg * 2 + 1];
        float be = beta[c] - stats[bg * 2] * ga;
        float4 v = *(const float4*)(xb + (size_t)cl * NSPAT + nl);
        u16* dst = &t[cl * TSTR + nl];
        dst[0] = f2bf(v.x * ga + be);
        dst[1] = f2bf(v.y * ga + be);
        dst[2] = f2bf(v.z * ga + be);
        dst[3] = f2bf(v.w * ga + be);
    }
    __syncthreads();
    u16* hb = hT + ((size_t)b * NSPAT + n0) * CDIM + c0;
#pragma unroll
    for (int p = 0; p < 4; ++p) {
        int nl = p * 16 + (tid >> 4);
        int cl4 = (tid & 15) << 2;
        ushort4 o;
        o.x = t[(cl4 + 0) * TSTR + nl];
        o.y = t[(cl4 + 1) * TSTR + nl];
        o.z = t[(cl4 + 2) * TSTR + nl];
        o.w = t[(cl4 + 3) * TSTR + nl];
        *(ushort4*)(hb + (size_t)nl * CDIM + cl4) = o;
    }
}

// ---------------- shared 128x128x64 MFMA core (global_load_lds + XOR swizzle, conflict-free) ----------------
__device__ __forceinline__ void gemm_core(
    const u16* __restrict__ Ab, const u16* __restrict__ Bb, int K, int lda, int ldb,
    int m0, int n0, u16* As, u16* Bs, floatx4 (&acc)[4][4]) {
    int tid = threadIdx.x;
    int lane = tid & 63, wave = tid >> 6, quad = lane >> 4, lrow = lane & 15;
    int wm = (wave >> 1) << 6, wn = (wave & 1) << 6;
    for (int k0 = 0; k0 < K; k0 += 64) {
#pragma unroll
        for (int it = 0; it < 4; ++it) {
            int c = it * 256 + tid;             // 1024 chunks of 16B per operand tile
            int r = c >> 3, p = c & 7;
            int kc = p ^ (r & 7);               // slot p holds global chunk p^(r&7)
            load_lds16(Ab + (size_t)(m0 + r) * lda + k0 + (kc << 3), &As[c << 3]);
            load_lds16(Bb + (size_t)(n0 + r) * ldb + k0 + (kc << 3), &Bs[c << 3]);
        }
        __syncthreads();
#pragma unroll
        for (int s = 0; s < 2; ++s) {
            short8 af[4], bf[4];
#pragma unroll
            for (int i = 0; i < 4; ++i) {
                int R = wm + i * 16 + lrow;
                int p = (s * 4 + quad) ^ (R & 7);
                af[i] = *(const short8*)&As[(R << 6) + (p << 3)];
            }
#pragma unroll
            for (int j = 0; j < 4; ++j) {
                int R = wn + j * 16 + lrow;
                int p = (s * 4 + quad) ^ (R & 7);
                bf[j] = *(const short8*)&Bs[(R << 6) + (p << 3)];
            }
#pragma unroll
            for (int i = 0; i < 4; ++i)
#pragma unroll
                for (int j = 0; j < 4; ++j)
                    acc[i][j] = __builtin_amdgcn_mfma_f32_16x16x32_bf16(af[i], bf[j], acc[i][j], 0, 0, 0);
        }
        __syncthreads();
    }
}

#define ACC_INIT floatx4 acc[4][4]; \
    _Pragma("unroll") for (int i = 0; i < 4; ++i) \
    _Pragma("unroll") for (int j = 0; j < 4; ++j) acc[i][j] = (floatx4){0.f, 0.f, 0.f, 0.f};

// ---------------- qkv: qkvT[b][n][o] = (W_qkv . h)^T + bias, all transposed ----------------
__global__ __launch_bounds__(256) void qkv_kernel(
    const u16* __restrict__ wqkv, const u16* __restrict__ hT, const float* __restrict__ bias,
    u16* __restrict__ qkvT) {
    __shared__ u16 As[128 * 64];
    __shared__ u16 Bs[128 * 64];
    int m0 = blockIdx.y << 7, n0 = blockIdx.x << 7;
    const u16* Bb = hT + (size_t)blockIdx.z * CDIM * NSPAT;
    ACC_INIT;
    gemm_core(wqkv, Bb, CDIM, CDIM, CDIM, m0, n0, As, Bs, acc);
    int lane = threadIdx.x & 63, wave = threadIdx.x >> 6;
    int quad = lane >> 4, lrow = lane & 15;
    int wm = (wave >> 1) << 6, wn = (wave & 1) << 6;
    u16* qk = qkvT + (size_t)blockIdx.z * NSPAT * QKV3;
#pragma unroll
    for (int i = 0; i < 4; ++i)
#pragma unroll
        for (int j = 0; j < 4; ++j) {
            int R0 = m0 + wm + i * 16 + (quad << 2);
            int Cc = n0 + wn + j * 16 + lrow;
            ushort4 pk;
            pk.x = f2bf(acc[i][j][0] + bias[R0 + 0]);
            pk.y = f2bf(acc[i][j][1] + bias[R0 + 1]);
            pk.z = f2bf(acc[i][j][2] + bias[R0 + 2]);
            pk.w = f2bf(acc[i][j][3] + bias[R0 + 3]);
            *(ushort4*)&qk[(size_t)Cc * QKV3 + R0] = pk;
        }
}

// ---------------- scores+WV merged: y<8 -> P=exp(qk^T*scale)+lsums ; y>=8 -> WV=W_proj.V ----------------
__global__ __launch_bounds__(256) void scores_wv_kernel(
    const u16* __restrict__ qkvT, const u16* __restrict__ wproj,
    u16* __restrict__ P, float* __restrict__ lsums, u16* __restrict__ WV, float scale) {
    __shared__ u16 As[128 * 64];
    __shared__ u16 Bs[128 * 64];
    int z = blockIdx.z;
    const u16* qb = qkvT + (size_t)z * NSPAT * QKV3;
    int n0 = blockIdx.x << 7;
    int lane = threadIdx.x & 63, wave = threadIdx.x >> 6;
    int quad = lane >> 4, lrow = lane & 15;
    int wm = (wave >> 1) << 6, wn = (wave & 1) << 6;

    if (blockIdx.y < 8) {  // ---- scores: A=q^T rows i, B=k^T rows j (both k-contig, lda 1536)
        int m0 = blockIdx.y << 7;
        ACC_INIT;
        gemm_core(qb, qb + CDIM, CDIM, QKV3, QKV3, m0, n0, As, Bs, acc);
        u16* Pp = P + (size_t)z * NSPAT * NSPAT;
        float rowpart[4][4];
#pragma unroll
        for (int i = 0; i < 4; ++i)
#pragma unroll
            for (int r = 0; r < 4; ++r) rowpart[i][r] = 0.f;
#pragma unroll
        for (int i = 0; i < 4; ++i)
#pragma unroll
            for (int j = 0; j < 4; ++j)
#pragma unroll
                for (int r = 0; r < 4; ++r) {
                    int R = m0 + wm + i * 16 + (quad << 2) + r;
                    int Cc = n0 + wn + j * 16 + lrow;
                    float e = __expf(acc[i][j][r] * scale);
                    rowpart[i][r] += e;
                    Pp[(size_t)R * NSPAT + Cc] = f2bf(e);
                }
#pragma unroll
        for (int i = 0; i < 4; ++i)
#pragma unroll
            for (int r = 0; r < 4; ++r) {
                float v = rowpart[i][r];
#pragma unroll
                for (int m = 1; m < 16; m <<= 1) v += __shfl_xor(v, m);
                if (lrow == 0) {
                    int R = m0 + wm + i * 16 + (quad << 2) + r;
                    atomicAdd(&lsums[(size_t)z * NSPAT + R], v);
                }
            }
    } else {  // ---- WV[o][j] = sum_c wproj[o][c] * vT[j][c]
        int m0 = (blockIdx.y - 8) << 7;
        ACC_INIT;
        gemm_core(wproj, qb + 2 * CDIM, CDIM, CDIM, QKV3, m0, n0, As, Bs, acc);
        u16* Wp = WV + (size_t)z * CDIM * NSPAT;
#pragma unroll
        for (int i = 0; i < 4; ++i)
#pragma unroll
            for (int j = 0; j < 4; ++j)
#pragma unroll
                for (int r = 0; r < 4; ++r) {
                    int R = m0 + wm + i * 16 + (quad << 2) + r;
                    int Cc = n0 + wn + j * 16 + lrow;
                    Wp[(size_t)R * NSPAT + Cc] = f2bf(acc[i][j][r]);
                }
    }
}

// ---------------- final: out[o][i] = (sum_j WV[o][j] P[i][j]) / l[i] + bias[o] + x[o][i] ----------------
__global__ __launch_bounds__(256) void final_kernel(
    const u16* __restrict__ WV, const u16* __restrict__ P, const float* __restrict__ lsums,
    const float* __restrict__ bias, const float* __restrict__ x, float* __restrict__ out) {
    __shared__ u16 As[128 * 64];
    __shared__ u16 Bs[128 * 64];
    int z = blockIdx.z;
    int m0 = blockIdx.y << 7, n0 = blockIdx.x << 7;
    const u16* Ab = WV + (size_t)z * CDIM * NSPAT;
    const u16* Bb = P + (size_t)z * NSPAT * NSPAT;
    ACC_INIT;
    gemm_core(Ab, Bb, NSPAT, NSPAT, NSPAT, m0, n0, As, Bs, acc);
    int lane = threadIdx.x & 63, wave = threadIdx.x >> 6;
    int quad = lane >> 4, lrow = lane & 15;
    int wm = (wave >> 1) << 6, wn = (wave & 1) << 6;
    float* Op = out + (size_t)z * CDIM * NSPAT;
    const float* xr = x + (size_t)z * CDIM * NSPAT;
    const float* li = lsums + (size_t)z * NSPAT;
#pragma unroll
    for (int i = 0; i < 4; ++i)
#pragma unroll
        for (int j = 0; j < 4; ++j) {
            int Cc = n0 + wn + j * 16 + lrow;
            float sc = __builtin_amdgcn_rcpf(li[Cc]);
#pragma unroll
            for (int r = 0; r < 4; ++r) {
                int R = m0 + wm + i * 16 + (quad << 2) + r;
                size_t off = (size_t)R * NSPAT + Cc;
                Op[off] = acc[i][j][r] * sc + bias[R] + xr[off];
            }
        }
}

// ---------------- launch ----------------
extern "C" void kernel_launch(void* const* d_in, const int* in_sizes, int n_in,
                              void* d_out, int out_size, void* d_ws, size_t ws_size,
                              hipStream_t stream) {
    const float* x      = (const float*)d_in[0];
    const float* gamma  = (const float*)d_in[1];
    const float* beta   = (const float*)d_in[2];
    const float* w_qkv  = (const float*)d_in[3];
    const float* b_qkv  = (const float*)d_in[4];
    const float* w_proj = (const float*)d_in[5];
    const float* b_proj = (const float*)d_in[6];
    float* out = (float*)d_out;

    const size_t CN = (size_t)CDIM * NSPAT;   // 524288
    const size_t NN = (size_t)NSPAT * NSPAT;  // 1048576
    const float SCALE = 0.044194173824159216f;

    // Workspace (~120 MB; ws >= 186.5 MB proven in round 4):
    char* ws = (char*)d_ws;
    float* stats  = (float*)ws;                                   // 4 KB
    u16* wqkv_bf  = (u16*)(ws + 4096);                            // 1.5 MB
    u16* wproj_bf = wqkv_bf + (size_t)3 * CDIM * CDIM;            // 0.5 MB
    u16* hT       = wproj_bf + (size_t)CDIM * CDIM;               // 16.8 MB  [n][c] bf16
    u16* qkvT     = hT + BATCH * CN;                              // 50.3 MB  [n][o:1536] bf16
    u16* WV       = qkvT + (size_t)BATCH * NSPAT * QKV3;          // 16.8 MB  [o][j] bf16
    u16* P        = WV + BATCH * CN;                              // 33.5 MB  [i][j] bf16 (unnorm)
    float* lsums  = (float*)(P + BATCH * NN);                     // 64 KB

    prep_kernel<<<1168, 256, 0, stream>>>(w_qkv, w_proj, wqkv_bf, wproj_bf, x, stats, lsums);

    gn_transpose_kernel<<<dim3(NSPAT / 64, CDIM / 64, BATCH), 256, 0, stream>>>(
        x, gamma, beta, stats, hT);

    // qkv: M=1536, N=1024, K=512 -> qkvT[b][n][1536] (+bias), all transposed
    qkv_kernel<<<dim3(8, 12, BATCH), 256, 0, stream>>>(wqkv_bf, hT, b_qkv, qkvT);

    // scores (y<8): P=exp(scale*q^T k) + lsums ; WV (y>=8): W_proj.V -> WV[o][j]
    scores_wv_kernel<<<dim3(8, 12, BATCH), 256, 0, stream>>>(
        qkvT, wproj_bf, P, lsums, WV, SCALE);

    // final: M=o 512, N=i 1024, K=j 1024; epilogue /l[i] + b_proj + x
    final_kernel<<<dim3(8, 4, BATCH), 256, 0, stream>>>(WV, P, lsums, b_proj, x, out);
}

// Round 10
// 240.376 us; speedup vs baseline: 1.0764x; 1.0484x over previous
//
#include <hip/hip_runtime.h>
#include <hip/hip_bf16.h>

typedef unsigned short u16;
typedef unsigned int u32;
typedef __attribute__((ext_vector_type(8))) short short8;
typedef __attribute__((ext_vector_type(4))) float floatx4;

#define BATCH 16
#define CDIM 512
#define NSPAT 1024
#define NGROUP 8

__device__ __forceinline__ u16 f2bf(float f) {
    unsigned u = __float_as_uint(f);
    u += 0x7FFFu + ((u >> 16) & 1u);   // RNE
    return (u16)(u >> 16);
}
__device__ __forceinline__ u32 f2bf2(float lo, float hi) {   // packed v_cvt_pk_bf16_f32
    __hip_bfloat162 h = __float22bfloat162_rn(make_float2(lo, hi));
    return *(u32*)&h;
}

__device__ __forceinline__ void load_lds16(const void* g, void* l) {
    __builtin_amdgcn_global_load_lds(
        (const __attribute__((address_space(1))) unsigned int*)g,
        (__attribute__((address_space(3))) unsigned int*)l, 16, 0, 0);
}

// ================= D1 prep =================
// blocks [0,512): w_qkv rows 0..1023 cvt -> wmega rows 0..1023
//        [512,768): w_proj cvt -> wproj_bf
//        [768,832): w_v transpose+cvt -> wv_t[ci][m]
//        [832,960): GroupNorm stats
//        [960,976): lsums zero
//        [976,984): bpv[o] = sum_c w_proj[o][c] * b_qkv[1024+c]
__global__ __launch_bounds__(256) void prep_kernel(
    const float* __restrict__ w_qkv, const float* __restrict__ w_proj,
    const float* __restrict__ b_qkv, const float* __restrict__ x,
    u16* __restrict__ wmega, u16* __restrict__ wproj_bf, u16* __restrict__ wv_t,
    float* __restrict__ stats, float* __restrict__ lsums, float* __restrict__ bpv) {
    int b = blockIdx.x;
    int tid = threadIdx.x;
    if (b < 768) {
        const float* src = (b < 512) ? w_qkv : w_proj;
        u16* dst = (b < 512) ? wmega : wproj_bf;
        int i = (b < 512 ? b : b - 512) * 256 + tid;
        float4 v = ((const float4*)src)[i];
        u32* d = (u32*)dst;
        d[i * 2] = f2bf2(v.x, v.y);
        d[i * 2 + 1] = f2bf2(v.z, v.w);
        return;
    }
    if (b < 832) {  // transpose w_v (rows 1024..1535 of w_qkv) -> wv_t[ci][m], 64x64 tiles
        __shared__ u16 t[64 * 66];
        int bt = b - 768;
        int tx = bt & 7, ty = bt >> 3;          // tx: ci-tile, ty: m-tile
        const float* src = w_qkv + (size_t)(1024 + ty * 64) * CDIM + tx * 64;
#pragma unroll
        for (int p = 0; p < 4; ++p) {
            int r = p * 16 + (tid >> 4);        // m within tile
            int c4 = (tid & 15) << 2;           // ci within tile
            float4 v = *(const float4*)(src + (size_t)r * CDIM + c4);
            u16* d = &t[r * 66 + c4];
            d[0] = f2bf(v.x); d[1] = f2bf(v.y); d[2] = f2bf(v.z); d[3] = f2bf(v.w);
        }
        __syncthreads();
        u16* dst = wv_t + (size_t)(tx * 64) * CDIM + ty * 64;
#pragma unroll
        for (int p = 0; p < 4; ++p) {
            int c = p * 16 + (tid >> 4);        // ci within tile
            int r4 = (tid & 15) << 2;           // m within tile
            ushort4 o;
            o.x = t[(r4 + 0) * 66 + c];
            o.y = t[(r4 + 1) * 66 + c];
            o.z = t[(r4 + 2) * 66 + c];
            o.w = t[(r4 + 3) * 66 + c];
            *(ushort4*)(dst + (size_t)c * CDIM + r4) = o;
        }
        return;
    }
    if (b < 960) {  // stats
        __shared__ float rs[4], rss[4];
        int bg = b - 832;
        const float4* xv = (const float4*)(x + (size_t)bg * 65536);
        float s = 0.f, ss = 0.f;
        for (int i = tid; i < 16384; i += 256) {
            float4 v = xv[i];
            s += v.x + v.y + v.z + v.w;
            ss += v.x * v.x + v.y * v.y + v.z * v.z + v.w * v.w;
        }
#pragma unroll
        for (int off = 32; off; off >>= 1) { s += __shfl_down(s, off); ss += __shfl_down(ss, off); }
        int wave = tid >> 6, lane = tid & 63;
        if (lane == 0) { rs[wave] = s; rss[wave] = ss; }
        __syncthreads();
        if (tid == 0) {
            float S1 = rs[0] + rs[1] + rs[2] + rs[3];
            float S2 = rss[0] + rss[1] + rss[2] + rss[3];
            float mean = S1 * (1.f / 65536.f);
            float var = S2 * (1.f / 65536.f) - mean * mean;
            stats[bg * 2] = mean;
            stats[bg * 2 + 1] = rsqrtf(var + 1e-5f);
        }
        return;
    }
    if (b < 976) {  // zero lsums
        ((float4*)lsums)[(b - 960) * 256 + tid] = (float4){0.f, 0.f, 0.f, 0.f};
        return;
    }
    {   // bpv: 8 blocks x 64 rows; one wave per row iteration
        int o0 = (b - 976) * 64;
        int wave = tid >> 6, lane = tid & 63;
        const float4* bvv = (const float4*)(b_qkv + 1024);
        float4 v0 = bvv[lane * 2], v1 = bvv[lane * 2 + 1];
        for (int it = 0; it < 16; ++it) {
            int o = o0 + wave * 16 + it;
            const float4* wr = (const float4*)(w_proj + (size_t)o * CDIM);
            float4 a0 = wr[lane * 2], a1 = wr[lane * 2 + 1];
            float s = a0.x * v0.x + a0.y * v0.y + a0.z * v0.z + a0.w * v0.w
                    + a1.x * v1.x + a1.y * v1.y + a1.z * v1.z + a1.w * v1.w;
#pragma unroll
            for (int off = 32; off; off >>= 1) s += __shfl_down(s, off);
            if (lane == 0) bpv[o] = s;
        }
    }
}

// ================= shared 128x128x64 MFMA core (global_load_lds + XOR swizzle) =================
__device__ __forceinline__ void gemm_core(
    const u16* __restrict__ Ab, const u16* __restrict__ Bb, int K, int lda, int ldb,
    int m0, int n0, u16* As, u16* Bs, floatx4 (&acc)[4][4]) {
    int tid = threadIdx.x;
    int lane = tid & 63, wave = tid >> 6, quad = lane >> 4, lrow = lane & 15;
    int wm = (wave >> 1) << 6, wn = (wave & 1) << 6;
    for (int k0 = 0; k0 < K; k0 += 64) {
#pragma unroll
        for (int it = 0; it < 4; ++it) {
            int c = it * 256 + tid;
            int r = c >> 3, p = c & 7;
            int kc = p ^ (r & 7);               // slot p holds global chunk p^(r&7)
            load_lds16(Ab + (size_t)(m0 + r) * lda + k0 + (kc << 3), &As[c << 3]);
            load_lds16(Bb + (size_t)(n0 + r) * ldb + k0 + (kc << 3), &Bs[c << 3]);
        }
        __syncthreads();
#pragma unroll
        for (int s = 0; s < 2; ++s) {
            short8 af[4], bf[4];
#pragma unroll
            for (int i = 0; i < 4; ++i) {
                int R = wm + i * 16 + lrow;
                int p = (s * 4 + quad) ^ (R & 7);
                af[i] = *(const short8*)&As[(R << 6) + (p << 3)];
            }
#pragma unroll
            for (int j = 0; j < 4; ++j) {
                int R = wn + j * 16 + lrow;
                int p = (s * 4 + quad) ^ (R & 7);
                bf[j] = *(const short8*)&Bs[(R << 6) + (p << 3)];
            }
#pragma unroll
            for (int i = 0; i < 4; ++i)
#pragma unroll
                for (int j = 0; j < 4; ++j)
                    acc[i][j] = __builtin_amdgcn_mfma_f32_16x16x32_bf16(af[i], bf[j], acc[i][j], 0, 0, 0);
        }
        __syncthreads();
    }
}

#define ACC_INIT floatx4 acc[4][4]; \
    _Pragma("unroll") for (int i = 0; i < 4; ++i) \
    _Pragma("unroll") for (int j = 0; j < 4; ++j) acc[i][j] = (floatx4){0.f, 0.f, 0.f, 0.f};

// ================= D2: GN apply+transpose (z<16) + Wpv GEMM (z==16) =================
#define TSTR 66
__global__ __launch_bounds__(256) void gn_wpv_kernel(
    const float* __restrict__ x, const float* __restrict__ gamma, const float* __restrict__ beta,
    const float* __restrict__ stats, u16* __restrict__ hT,
    const u16* __restrict__ wproj_bf, const u16* __restrict__ wv_t, u16* __restrict__ wmega) {
    __shared__ u16 smem[2 * 128 * 64];
    int tid = threadIdx.x;
    if (blockIdx.z == 16) {  // Wpv = wproj_bf . wv_t^T -> wmega rows 1024..1535
        if (blockIdx.x >= 4 || blockIdx.y >= 4) return;
        int m0 = blockIdx.y << 7, n0 = blockIdx.x << 7;
        ACC_INIT;
        gemm_core(wproj_bf, wv_t, CDIM, CDIM, CDIM, m0, n0, smem, smem + 128 * 64, acc);
        int lane = tid & 63, wave = tid >> 6;
        int quad = lane >> 4, lrow = lane & 15;
        int wm = (wave >> 1) << 6, wn = (wave & 1) << 6;
#pragma unroll
        for (int i = 0; i < 4; ++i)
#pragma unroll
            for (int j = 0; j < 4; ++j)
#pragma unroll
                for (int r = 0; r < 4; ++r) {
                    int R = m0 + wm + i * 16 + (quad << 2) + r;
                    int Cc = n0 + wn + j * 16 + lrow;
                    wmega[(size_t)(1024 + R) * CDIM + Cc] = f2bf(acc[i][j][r]);
                }
        return;
    }
    u16* t = smem;
    int b = blockIdx.z, c0 = blockIdx.y << 6, n0 = blockIdx.x << 6;
    const float* xb = x + ((size_t)b * CDIM + c0) * NSPAT + n0;
#pragma unroll
    for (int p = 0; p < 4; ++p) {
        int cl = p * 16 + (tid >> 4);
        int nl = (tid & 15) << 2;
        int c = c0 + cl;
        int bg = b * NGROUP + (c >> 6);
        float ga = gamma[c] * stats[bg * 2 + 1];
        float be = beta[c] - stats[bg * 2] * ga;
        float4 v = *(const float4*)(xb + (size_t)cl * NSPAT + nl);
        u16* dst = &t[cl * TSTR + nl];
        dst[0] = f2bf(v.x * ga + be);
        dst[1] = f2bf(v.y * ga + be);
        dst[2] = f2bf(v.z * ga + be);
        dst[3] = f2bf(v.w * ga + be);
    }
    __syncthreads();
    u16* hb = hT + ((size_t)b * NSPAT + n0) * CDIM + c0;
#pragma unroll
    for (int p = 0; p < 4; ++p) {
        int nl = p * 16 + (tid >> 4);
        int cl4 = (tid & 15) << 2;
        ushort4 o;
        o.x = t[(cl4 + 0) * TSTR + nl];
        o.y = t[(cl4 + 1) * TSTR + nl];
        o.z = t[(cl4 + 2) * TSTR + nl];
        o.w = t[(cl4 + 3) * TSTR + nl];
        *(ushort4*)(hb + (size_t)nl * CDIM + cl4) = o;
    }
}

// ================= D3: qkv-mega: [q;k;WV] = wmega . h + [b_qkv(qk); bpv] =================
// grid (BATCH, 8, 12): batch in x for XCD affinity.
__global__ __launch_bounds__(256) void qkv_kernel(
    const u16* __restrict__ wmega, const u16* __restrict__ hT,
    const float* __restrict__ b_qkv, const float* __restrict__ bpv,
    u16* __restrict__ qkT, u16* __restrict__ WV) {
    __shared__ u16 As[128 * 64];
    __shared__ u16 Bs[128 * 64];
    int z = blockIdx.x;                      // batch
    int n0 = blockIdx.y << 7;
    int m0 = blockIdx.z << 7;
    const u16* Bb = hT + (size_t)z * CDIM * NSPAT;
    ACC_INIT;
    gemm_core(wmega, Bb, CDIM, CDIM, CDIM, m0, n0, As, Bs, acc);
    int lane = threadIdx.x & 63, wave = threadIdx.x >> 6;
    int quad = lane >> 4, lrow = lane & 15;
    int wm = (wave >> 1) << 6, wn = (wave & 1) << 6;
    if (blockIdx.z < 8) {  // q,k rows: transposed packed store to qkT[n][o], ldc=1024
        u16* qk = qkT + (size_t)z * NSPAT * NSPAT;
#pragma unroll
        for (int i = 0; i < 4; ++i)
#pragma unroll
            for (int j = 0; j < 4; ++j) {
                int R0 = m0 + wm + i * 16 + (quad << 2);
                int Cc = n0 + wn + j * 16 + lrow;
                uint2 u;
                u.x = f2bf2(acc[i][j][0] + b_qkv[R0 + 0], acc[i][j][1] + b_qkv[R0 + 1]);
                u.y = f2bf2(acc[i][j][2] + b_qkv[R0 + 2], acc[i][j][3] + b_qkv[R0 + 3]);
                *(uint2*)&qk[(size_t)Cc * NSPAT + R0] = u;
            }
    } else {  // WV rows: natural store WV[o][n] + bpv
        u16* Wp = WV + (size_t)z * CDIM * NSPAT;
#pragma unroll
        for (int i = 0; i < 4; ++i)
#pragma unroll
            for (int j = 0; j < 4; ++j)
#pragma unroll
                for (int r = 0; r < 4; ++r) {
                    int R = m0 - 1024 + wm + i * 16 + (quad << 2) + r;
                    int Cc = n0 + wn + j * 16 + lrow;
                    Wp[(size_t)R * NSPAT + Cc] = f2bf(acc[i][j][r] + bpv[R]);
                }
    }
}

// ================= D4: scores: P = exp(scale * q^T k), fused row sums =================
// grid (BATCH, 8, 8): batch in x.
__global__ __launch_bounds__(256) void scores_kernel(
    const u16* __restrict__ qkT, u16* __restrict__ P, float* __restrict__ lsums, float scale) {
    __shared__ u16 As[128 * 64];
    __shared__ u16 Bs[128 * 64];
    int z = blockIdx.x;
    int n0 = blockIdx.y << 7;                // j tile
    int m0 = blockIdx.z << 7;                // i tile
    const u16* qb = qkT + (size_t)z * NSPAT * NSPAT;
    ACC_INIT;
    gemm_core(qb, qb + CDIM, CDIM, NSPAT, NSPAT, m0, n0, As, Bs, acc);
    int lane = threadIdx.x & 63, wave = threadIdx.x >> 6;
    int quad = lane >> 4, lrow = lane & 15;
    int wm = (wave >> 1) << 6, wn = (wave & 1) << 6;
    u16* Pp = P + (size_t)z * NSPAT * NSPAT;
    float rowpart[4][4];
#pragma unroll
    for (int i = 0; i < 4; ++i)
#pragma unroll
        for (int r = 0; r < 4; ++r) rowpart[i][r] = 0.f;
#pragma unroll
    for (int i = 0; i < 4; ++i)
#pragma unroll
        for (int j = 0; j < 4; ++j)
#pragma unroll
            for (int r = 0; r < 4; ++r) {
                int R = m0 + wm + i * 16 + (quad << 2) + r;
                int Cc = n0 + wn + j * 16 + lrow;
                float e = __expf(acc[i][j][r] * scale);
                rowpart[i][r] += e;
                Pp[(size_t)R * NSPAT + Cc] = f2bf(e);
            }
#pragma unroll
    for (int i = 0; i < 4; ++i)
#pragma unroll
        for (int r = 0; r < 4; ++r) {
            float v = rowpart[i][r];
#pragma unroll
            for (int m = 1; m < 16; m <<= 1) v += __shfl_xor(v, m);
            if (lrow == 0) {
                int R = m0 + wm + i * 16 + (quad << 2) + r;
                atomicAdd(&lsums[(size_t)z * NSPAT + R], v);
            }
        }
}

// ================= D5: final: out[o][i] = (sum_j WV[o][j] P[i][j]) / l[i] + b_proj[o] + x[o][i] =================
// grid (BATCH, 8, 4): batch in x.
__global__ __launch_bounds__(256) void final_kernel(
    const u16* __restrict__ WV, const u16* __restrict__ P, const float* __restrict__ lsums,
    const float* __restrict__ bias, const float* __restrict__ x, float* __restrict__ out) {
    __shared__ u16 As[128 * 64];
    __shared__ u16 Bs[128 * 64];
    int z = blockIdx.x;
    int n0 = blockIdx.y << 7;                // i tile
    int m0 = blockIdx.z << 7;                // o tile
    const u16* Ab = WV + (size_t)z * CDIM * NSPAT;
    const u16* Bb = P + (size_t)z * NSPAT * NSPAT;
    ACC_INIT;
    gemm_core(Ab, Bb, NSPAT, NSPAT, NSPAT, m0, n0, As, Bs, acc);
    int lane = threadIdx.x & 63, wave = threadIdx.x >> 6;
    int quad = lane >> 4, lrow = lane & 15;
    int wm = (wave >> 1) << 6, wn = (wave & 1) << 6;
    float* Op = out + (size_t)z * CDIM * NSPAT;
    const float* xr = x + (size_t)z * CDIM * NSPAT;
    const float* li = lsums + (size_t)z * NSPAT;
#pragma unroll
    for (int i = 0; i < 4; ++i)
#pragma unroll
        for (int j = 0; j < 4; ++j) {
            int Cc = n0 + wn + j * 16 + lrow;
            float sc = __builtin_amdgcn_rcpf(li[Cc]);
#pragma unroll
            for (int r = 0; r < 4; ++r) {
                int R = m0 + wm + i * 16 + (quad << 2) + r;
                size_t off = (size_t)R * NSPAT + Cc;
                Op[off] = acc[i][j][r] * sc + bias[R] + xr[off];
            }
        }
}

// ================= launch =================
extern "C" void kernel_launch(void* const* d_in, const int* in_sizes, int n_in,
                              void* d_out, int out_size, void* d_ws, size_t ws_size,
                              hipStream_t stream) {
    const float* x      = (const float*)d_in[0];
    const float* gamma  = (const float*)d_in[1];
    const float* beta   = (const float*)d_in[2];
    const float* w_qkv  = (const float*)d_in[3];
    const float* b_qkv  = (const float*)d_in[4];
    const float* w_proj = (const float*)d_in[5];
    const float* b_proj = (const float*)d_in[6];
    float* out = (float*)d_out;

    const size_t CN = (size_t)CDIM * NSPAT;   // 524288
    const size_t NN = (size_t)NSPAT * NSPAT;  // 1048576
    const float SCALE = 0.044194173824159216f;

    // Workspace (~103 MB; ws >= 186.5 MB proven in round 4):
    char* ws = (char*)d_ws;
    float* stats   = (float*)ws;                              // 1 KB
    float* bpv     = (float*)(ws + 1024);                     // 2 KB
    u16* wmega     = (u16*)(ws + 4096);                       // 1536x512 bf16: [Wq;Wk;Wpv]
    u16* wproj_bf  = wmega + (size_t)3 * CDIM * CDIM;         // 0.5 MB
    u16* wv_t      = wproj_bf + (size_t)CDIM * CDIM;          // 0.5 MB  Wv^T[ci][m]
    u16* hT        = wv_t + (size_t)CDIM * CDIM;              // 16.8 MB [n][c]
    u16* qkT       = hT + BATCH * CN;                         // 33.5 MB [n][q,k:1024]
    u16* WV        = qkT + BATCH * NN;                        // 16.8 MB [o][n]
    u16* P         = WV + BATCH * CN;                         // 33.5 MB [i][j] unnorm
    float* lsums   = (float*)(P + BATCH * NN);                // 64 KB

    prep_kernel<<<984, 256, 0, stream>>>(
        w_qkv, w_proj, b_qkv, x, wmega, wproj_bf, wv_t, stats, lsums, bpv);

    gn_wpv_kernel<<<dim3(16, 8, 17), 256, 0, stream>>>(
        x, gamma, beta, stats, hT, wproj_bf, wv_t, wmega);

    qkv_kernel<<<dim3(BATCH, 8, 12), 256, 0, stream>>>(
        wmega, hT, b_qkv, bpv, qkT, WV);

    scores_kernel<<<dim3(BATCH, 8, 8), 256, 0, stream>>>(qkT, P, lsums, SCALE);

    final_kernel<<<dim3(BATCH, 8, 4), 256, 0, stream>>>(WV, P, lsums, b_proj, x, out);
}